// Round 6
// baseline (417.652 us; speedup 1.0000x reference)
//
#include <hip/hip_runtime.h>
#include <hip/hip_bf16.h>
#include <float.h>
#include <math.h>

typedef float f32x4 __attribute__((ext_vector_type(4)));
typedef short short8 __attribute__((ext_vector_type(8)));
typedef unsigned int uint32;

#define NB 4
#define SQ 4096
#define DM 4096
#define DH 128
#define LOG2E 1.44269504088896f
#define SCALE 0.0883883476483184f   // 1/sqrt(128)
#define SCL2 (SCALE * LOG2E)        // fold into log2 domain

__device__ __forceinline__ unsigned short f2bf(float f) {
  union { float f; unsigned u; } x; x.f = f;
  unsigned r = x.u + 0x7FFFu + ((x.u >> 16) & 1u);
  return (unsigned short)(r >> 16);
}

// ---------------- kernel 1: pack weights (bf16) + bias (f32) ----------------
__global__ void cast_w_kernel(const float* __restrict__ wq, const float* __restrict__ wk,
                              const float* __restrict__ wv, const float* __restrict__ bq,
                              const float* __restrict__ bk, const float* __restrict__ bv,
                              unsigned short* __restrict__ wb, float* __restrict__ biasws) {
  int t = blockIdx.x * 256 + threadIdx.x;  // 0..196607, each handles 8 elems
  int base = t * 8;
  int n = base >> 12;       // output row 0..383 (q:0-127, k:128-255, v:256-383)
  int d = base & 4095;
  const float* src = (n < 128) ? (wq + (size_t)n * DM)
                   : (n < 256) ? (wk + (size_t)(n - 128) * DM)
                               : (wv + (size_t)(n - 256) * DM);
  float4 f0 = *(const float4*)(src + d);
  float4 f1 = *(const float4*)(src + d + 4);
  short8 v;
  v[0] = (short)f2bf(f0.x); v[1] = (short)f2bf(f0.y);
  v[2] = (short)f2bf(f0.z); v[3] = (short)f2bf(f0.w);
  v[4] = (short)f2bf(f1.x); v[5] = (short)f2bf(f1.y);
  v[6] = (short)f2bf(f1.z); v[7] = (short)f2bf(f1.w);
  *(short8*)(wb + base) = v;
  if (t < 384) biasws[t] = (t < 128) ? bq[t] : (t < 256) ? bk[t - 128] : bv[t - 256];
}

// ---------------- kernel 2: fused QKV GEMM + bias + RoPE ----------------
// Barrier-free 1-wave blocks, NO LDS: both operands stream global->VGPR in
// MFMA fragment layout. BM=64, BN=64, acc 4x4; K in 32-chunks, 2-deep reg
// double-buffer (named c0/c1). A cast f32->bf16 in-register via cvt_pk.
// Grid 1536 = 256 m-tiles x 6 n-tiles = 6 blocks/CU; XCD mapping co-runs one
// m-tile's 6 n-blocks on one CU (x HBM-read once; re-reads from L1/L2).
struct CH { f32x4 a[4][2]; short8 b[4]; };

__device__ __forceinline__ short8 cvt8(f32x4 u, f32x4 v) {
  uint32 r0, r1, r2, r3;
  asm("v_cvt_pk_bf16_f32 %0, %1, %2" : "=v"(r0) : "v"(u[0]), "v"(u[1]));
  asm("v_cvt_pk_bf16_f32 %0, %1, %2" : "=v"(r1) : "v"(u[2]), "v"(u[3]));
  asm("v_cvt_pk_bf16_f32 %0, %1, %2" : "=v"(r2) : "v"(v[0]), "v"(v[1]));
  asm("v_cvt_pk_bf16_f32 %0, %1, %2" : "=v"(r3) : "v"(v[2]), "v"(v[3]));
  union { uint32 w[4]; short8 s; } z;
  z.w[0] = r0; z.w[1] = r1; z.w[2] = r2; z.w[3] = r3;
  return z.s;
}

__device__ __forceinline__ void ldch(CH& c, const float* xp, const unsigned short* bp, int k) {
#pragma unroll
  for (int mi = 0; mi < 4; ++mi) {
    c.a[mi][0] = *(const f32x4*)(xp + (size_t)mi * 16 * DM + k);
    c.a[mi][1] = *(const f32x4*)(xp + (size_t)mi * 16 * DM + k + 4);
  }
#pragma unroll
  for (int ni = 0; ni < 4; ++ni)
    c.b[ni] = *(const short8*)(bp + (size_t)ni * 16 * DM + k);
}

__device__ __forceinline__ void step(f32x4 (&acc)[4][4], CH& c,
                                     const float* xp, const unsigned short* bp, int knext) {
  short8 af[4];
#pragma unroll
  for (int mi = 0; mi < 4; ++mi) af[mi] = cvt8(c.a[mi][0], c.a[mi][1]);
  // c.a dead -> reload for knext (loads fly during the MFMA cluster below)
#pragma unroll
  for (int mi = 0; mi < 4; ++mi) {
    c.a[mi][0] = *(const f32x4*)(xp + (size_t)mi * 16 * DM + knext);
    c.a[mi][1] = *(const f32x4*)(xp + (size_t)mi * 16 * DM + knext + 4);
  }
#pragma unroll
  for (int ni = 0; ni < 4; ++ni) {
    short8 bb = c.b[ni];
#pragma unroll
    for (int mi = 0; mi < 4; ++mi)
      acc[mi][ni] = __builtin_amdgcn_mfma_f32_16x16x32_bf16(af[mi], bb, acc[mi][ni], 0, 0, 0);
    c.b[ni] = *(const short8*)(bp + (size_t)ni * 16 * DM + knext);  // bb consumed
  }
}

__device__ __forceinline__ void finch(f32x4 (&acc)[4][4], CH& c) {
  short8 af[4];
#pragma unroll
  for (int mi = 0; mi < 4; ++mi) af[mi] = cvt8(c.a[mi][0], c.a[mi][1]);
#pragma unroll
  for (int ni = 0; ni < 4; ++ni)
#pragma unroll
    for (int mi = 0; mi < 4; ++mi)
      acc[mi][ni] = __builtin_amdgcn_mfma_f32_16x16x32_bf16(af[mi], c.b[ni], acc[mi][ni], 0, 0, 0);
}

__global__ __launch_bounds__(64, 2) void gemm_qkv_rope(
    const float* __restrict__ x, const unsigned short* __restrict__ wb,
    const float* __restrict__ biasws, const float* __restrict__ sing,
    const float* __restrict__ cosg, unsigned short* __restrict__ qb,
    unsigned short* __restrict__ kb, unsigned short* __restrict__ vb) {
  const int l = threadIdx.x;
  const int l15 = l & 15, lg = l >> 4;
  const int bid = blockIdx.x;
  const int xcd = bid & 7, loc = bid >> 3;
  const int mloc = loc / 6, nt = loc - mloc * 6;     // 32 m-tiles x 6 n-tiles per XCD
  const int m0 = (xcd * 32 + mloc) * 64;
  const int head = nt >> 1;                          // block-uniform

  const float* xp = x + (size_t)(m0 + l15) * DM + lg * 8;
  const unsigned short* bp = wb + (size_t)(nt * 64 + l15) * DM + lg * 8;

  f32x4 acc[4][4] = {};
  CH c0, c1;
  ldch(c0, xp, bp, 0);
  ldch(c1, xp, bp, 32);

#pragma unroll 1
  for (int t = 0; t < 63; ++t) {
    const int k = t * 64;
    step(acc, c0, xp, bp, k + 64);
    step(acc, c1, xp, bp, k + 96);
  }
  finch(acc, c0);
  finch(acc, c1);

  // epilogue: bias (+ RoPE for q,k — block-uniform), store bf16
  unsigned short* dst = (head == 0) ? qb : (head == 1) ? kb : vb;
#pragma unroll
  for (int mi = 0; mi < 4; ++mi)
#pragma unroll
    for (int ni = 0; ni < 4; ++ni) {
      int h = (nt & 1) * 64 + ni * 16 + l15;   // 0..127 within head
      float bias = biasws[head * 128 + h];
      f32x4 a = acc[mi][ni];
#pragma unroll
      for (int j2 = 0; j2 < 4; ++j2) {
        int row = m0 + mi * 16 + lg * 4 + j2;  // C/D: row=(lane>>4)*4+j
        float val = a[j2] + bias;
        if (head < 2) {
          // reference RoPE: out[h] = v[h]*cos[h] + v_sw[h]*sin[h],
          // v_sw[2i] = v_sw[2i+1] = v[2i+1] (odd element, repeated)
          int s = row & (SQ - 1);
          float cs = cosg[s * DH + h];
          float sn = sing[s * DH + h];
          float pr = __shfl_xor(val, 1, 64);      // partner col h^1 (same row)
          float sw = (l & 1) ? val : pr;          // odd h: self; even h: h+1
          val = val * cs + sw * sn;
        }
        dst[(size_t)row * DH + h] = f2bf(val);
      }
    }
}

// ---------------- kernel 2b: V -> V^T (per batch [128][4096]) ----------------
__global__ __launch_bounds__(256) void transpose_v(const unsigned short* __restrict__ vb,
                                                   unsigned short* __restrict__ vt) {
  __shared__ short T[128 * 72];
  const int b = blockIdx.x >> 6;
  const int s0 = (blockIdx.x & 63) * 64;
  const int t = threadIdx.x;
  {
    const int sl = t >> 2, dc = (t & 3) * 32;
    const unsigned short* src = vb + ((size_t)b * SQ + s0 + sl) * DH + dc;
#pragma unroll
    for (int i = 0; i < 4; ++i) {
      short8 v = *(const short8*)(src + i * 8);
#pragma unroll
      for (int j = 0; j < 8; ++j) T[(dc + i * 8 + j) * 72 + sl] = v[j];
    }
  }
  __syncthreads();
  {
    const int d = t >> 1, sh = (t & 1) * 32;
    unsigned short* dst = vt + ((size_t)b * DH + d) * SQ + s0 + sh;
#pragma unroll
    for (int i = 0; i < 4; ++i) {
      short8 w;
#pragma unroll
      for (int j = 0; j < 8; ++j) w[j] = T[d * 72 + sh + i * 8 + j];
      *(short8*)(dst + i * 8) = w;
    }
  }
}

// ---------------- kernel 3: causal flash attention ----------------
// 4 waves/block, one 16-row q-tile per block, KV steps strided across waves
// (flash-decoding split) with end merge. Swapped QK^T (S^T = K*Q): softmax is
// in-lane over 16 + 2 shuffles. Log2-domain scores. Defer-max (THR=8).
__global__ __launch_bounds__(256) void attn_kernel(
    const unsigned short* __restrict__ qb, const unsigned short* __restrict__ kb,
    const unsigned short* __restrict__ vt, float* __restrict__ out) {
  __shared__ __align__(16) float Obuf[3 * 16 * 132];  // 25344 B; aliased as P staging in loop
  __shared__ __align__(16) float Mlds[64];
  __shared__ __align__(16) float Llds[64];
  __shared__ __align__(16) float Clds[64];
  const int tid = threadIdx.x;
  const int w = tid >> 6, l = tid & 63;
  const int l15 = l & 15, lg = l >> 4;

  // schedule: slot = XCD (bi&7); 2 slots per batch; r-chunks balance CU totals
  const int bi = blockIdx.x;
  const int slot = bi & 7, p = slot & 1, batch = slot >> 1;
  const int idx = bi >> 3, ci = idx & 31, r = idx >> 5;
  const int a = ci + 32 * p;  // 0..63
  const int qt = (r == 0) ? a : (r == 1) ? 255 - a : (r == 2) ? 128 + a : 127 - a;
  const int q0 = qt * 16;
  const size_t bbase = (size_t)batch * SQ;
  const unsigned short* Kb = kb + bbase * DH;
  const unsigned short* Vt = vt + (size_t)batch * DH * SQ;
  short* Pw = (short*)Obuf + w * 1152;   // per-wave P staging [16][72] bf16

  // Q B-frags: col=l15 -> q row q0+l15; k-elems = kcd*32 + lg*8
  short8 qf[4];
  {
    const unsigned short* qp = qb + (bbase + q0 + l15) * DH + lg * 8;
#pragma unroll
    for (int kcd = 0; kcd < 4; ++kcd) qf[kcd] = *(const short8*)(qp + kcd * 32);
  }

  float m_r = -INFINITY, l_r = 0.f;
  f32x4 o[8] = {};
  const int nsteps = qt / 4 + 1;

  for (int st = w; st < nsteps; st += 4) {
    const int kv0 = st * 64;
    // --- K loads (A-frags: row=l15 -> kv, k=d) + QK^T ---
    short8 kf[4][4];
#pragma unroll
    for (int ni = 0; ni < 4; ++ni) {
      const unsigned short* kp = Kb + (size_t)(kv0 + ni * 16 + l15) * DH + lg * 8;
#pragma unroll
      for (int kcd = 0; kcd < 4; ++kcd) kf[ni][kcd] = *(const short8*)(kp + kcd * 32);
    }
    f32x4 sf[4] = {};
    __builtin_amdgcn_s_setprio(1);
#pragma unroll
    for (int kcd = 0; kcd < 4; ++kcd)
#pragma unroll
      for (int ni = 0; ni < 4; ++ni)
        sf[ni] = __builtin_amdgcn_mfma_f32_16x16x32_bf16(kf[ni][kcd], qf[kcd], sf[ni], 0, 0, 0);
    __builtin_amdgcn_s_setprio(0);

    // --- V^T loads issued early (consumed after softmax) ---
    short8 vf[8][2];
#pragma unroll
    for (int nd = 0; nd < 8; ++nd) {
      const unsigned short* vp = Vt + (size_t)(nd * 16 + l15) * SQ + kv0 + lg * 8;
      vf[nd][0] = *(const short8*)(vp);
      vf[nd][1] = *(const short8*)(vp + 32);
    }

    // --- scale (log2 domain) + causal mask (only diagonal step) ---
    float s[4][4];  // lane holds S^T[kv = kv0+ni*16+lg*4+j][q = q0+l15]
    if (st == nsteps - 1) {
#pragma unroll
      for (int ni = 0; ni < 4; ++ni)
#pragma unroll
        for (int j = 0; j < 4; ++j) {
          float v = sf[ni][j] * SCL2;
          if (kv0 + ni * 16 + lg * 4 + j > q0 + l15) v = -FLT_MAX;
          s[ni][j] = v;
        }
    } else {
#pragma unroll
      for (int ni = 0; ni < 4; ++ni)
#pragma unroll
        for (int j = 0; j < 4; ++j) s[ni][j] = sf[ni][j] * SCL2;
    }

    // --- softmax: in-lane max over 16, 2 shuffles across lg ---
    float tmx = s[0][0];
#pragma unroll
    for (int ni = 0; ni < 4; ++ni)
#pragma unroll
      for (int j = 0; j < 4; ++j) tmx = fmaxf(tmx, s[ni][j]);
    tmx = fmaxf(tmx, __shfl_xor(tmx, 16, 64));
    tmx = fmaxf(tmx, __shfl_xor(tmx, 32, 64));

    if (__any(tmx > m_r + 8.0f)) {          // defer-max: rescale only on real growth
      float mnew = fmaxf(m_r, tmx);
      float corr = exp2f(m_r - mnew);
      if (l < 16) Clds[w * 16 + l] = corr;  // redistribute corr q=l15 -> q=lg*4+j
      l_r *= corr; m_r = mnew;
      f32x4 c4 = *(f32x4*)&Clds[w * 16 + lg * 4];
#pragma unroll
      for (int nd = 0; nd < 8; ++nd)
#pragma unroll
        for (int j = 0; j < 4; ++j) o[nd][j] *= c4[j];
    }

    float rs = 0.f;
    float pp[4][4];
#pragma unroll
    for (int ni = 0; ni < 4; ++ni)
#pragma unroll
      for (int j = 0; j < 4; ++j) {
        pp[ni][j] = exp2f(s[ni][j] - m_r);
        rs += pp[ni][j];
      }
    rs += __shfl_xor(rs, 16, 64);
    rs += __shfl_xor(rs, 32, 64);
    l_r += rs;

    // --- P -> bf16 via cvt_pk, through per-wave LDS to A-frag layout ---
#pragma unroll
    for (int ni = 0; ni < 4; ++ni) {
      uint32 lo, hi;
      asm volatile("v_cvt_pk_bf16_f32 %0, %1, %2" : "=v"(lo) : "v"(pp[ni][0]), "v"(pp[ni][1]));
      asm volatile("v_cvt_pk_bf16_f32 %0, %1, %2" : "=v"(hi) : "v"(pp[ni][2]), "v"(pp[ni][3]));
      uint2 u; u.x = lo; u.y = hi;
      *(uint2*)&Pw[l15 * 72 + ni * 16 + lg * 4] = u;
    }
    short8 pa0 = *(short8*)&Pw[l15 * 72 + lg * 8];
    short8 pa1 = *(short8*)&Pw[l15 * 72 + 32 + lg * 8];
    __builtin_amdgcn_s_setprio(1);
#pragma unroll
    for (int nd = 0; nd < 8; ++nd) {
      o[nd] = __builtin_amdgcn_mfma_f32_16x16x32_bf16(pa0, vf[nd][0], o[nd], 0, 0, 0);
      o[nd] = __builtin_amdgcn_mfma_f32_16x16x32_bf16(pa1, vf[nd][1], o[nd], 0, 0, 0);
    }
    __builtin_amdgcn_s_setprio(0);
  }

  // --- merge the 4 waves' online states ---
  if (l < 16) { Mlds[w * 16 + l] = m_r; Llds[w * 16 + l] = l_r; }
  __syncthreads();   // P-staging region done; M/L visible
  if (w > 0) {
#pragma unroll
    for (int nd = 0; nd < 8; ++nd)
#pragma unroll
      for (int j = 0; j < 4; ++j)
        Obuf[(w - 1) * 2112 + (lg * 4 + j) * 132 + nd * 16 + l15] = o[nd][j];
  }
  __syncthreads();
  if (w == 0) {
    float al[4][4], Lt[4];
#pragma unroll
    for (int j = 0; j < 4; ++j) {
      int q = lg * 4 + j;
      float M = Mlds[q];
#pragma unroll
      for (int ww = 1; ww < 4; ++ww) M = fmaxf(M, Mlds[ww * 16 + q]);
      float sL = 0.f;
#pragma unroll
      for (int ww = 0; ww < 4; ++ww) {
        float aa = exp2f(Mlds[ww * 16 + q] - M);
        al[ww][j] = aa; sL += aa * Llds[ww * 16 + q];
      }
      Lt[j] = sL;
    }
#pragma unroll
    for (int nd = 0; nd < 8; ++nd)
#pragma unroll
      for (int j = 0; j < 4; ++j) {
        float acc2 = al[0][j] * o[nd][j];
#pragma unroll
        for (int ww = 1; ww < 4; ++ww)
          acc2 += al[ww][j] * Obuf[(ww - 1) * 2112 + (lg * 4 + j) * 132 + nd * 16 + l15];
        out[(bbase + q0 + lg * 4 + j) * DH + nd * 16 + l15] = acc2 / Lt[j];
      }
  }
}

extern "C" void kernel_launch(void* const* d_in, const int* in_sizes, int n_in,
                              void* d_out, int out_size, void* d_ws, size_t ws_size,
                              hipStream_t stream) {
  const float* x    = (const float*)d_in[0];
  const float* wq   = (const float*)d_in[1];
  const float* bq   = (const float*)d_in[2];
  const float* wk   = (const float*)d_in[3];
  const float* bk   = (const float*)d_in[4];
  const float* wv   = (const float*)d_in[5];
  const float* bv   = (const float*)d_in[6];
  const float* sing = (const float*)d_in[7];
  const float* cosg = (const float*)d_in[8];
  float* out = (float*)d_out;

  char* ws = (char*)d_ws;
  unsigned short* wb = (unsigned short*)ws;                        // 3,145,728 B
  float* biasws = (float*)(ws + 3145728);                          // 1,536 B
  unsigned short* qb = (unsigned short*)(ws + 3147264);            // 4 MB
  unsigned short* kb = (unsigned short*)(ws + 3147264 + 4194304);  // 4 MB
  unsigned short* vb = (unsigned short*)(ws + 3147264 + 2 * 4194304);  // 4 MB
  unsigned short* vt = (unsigned short*)(ws + 3147264 + 3 * 4194304);  // 4 MB (V^T)
  // total ws use: ~19.9 MB

  cast_w_kernel<<<768, 256, 0, stream>>>(wq, wk, wv, bq, bk, bv, wb, biasws);
  gemm_qkv_rope<<<1536, 64, 0, stream>>>(x, wb, biasws, sing, cosg, qb, kb, vb);
  transpose_v<<<256, 256, 0, stream>>>(vb, vt);
  attn_kernel<<<1024, 256, 0, stream>>>(qb, kb, vt, out);
}

// Round 7
// 240.700 us; speedup vs baseline: 1.7352x; 1.7352x over previous
//
#include <hip/hip_runtime.h>
#include <hip/hip_bf16.h>
#include <float.h>
#include <math.h>

typedef float f32x4 __attribute__((ext_vector_type(4)));
typedef short short8 __attribute__((ext_vector_type(8)));
typedef unsigned int uint32;

#define NB 4
#define SQ 4096
#define DM 4096
#define DH 128
#define LOG2E 1.44269504088896f
#define SCALE 0.0883883476483184f   // 1/sqrt(128)
#define SCL2 (SCALE * LOG2E)        // fold into log2 domain

__device__ __forceinline__ unsigned short f2bf(float f) {
  union { float f; unsigned u; } x; x.f = f;
  unsigned r = x.u + 0x7FFFu + ((x.u >> 16) & 1u);
  return (unsigned short)(r >> 16);
}

__device__ __forceinline__ uint2 cvt4(float4 f) {
  uint2 u;
  asm("v_cvt_pk_bf16_f32 %0, %1, %2" : "=v"(u.x) : "v"(f.x), "v"(f.y));
  asm("v_cvt_pk_bf16_f32 %0, %1, %2" : "=v"(u.y) : "v"(f.z), "v"(f.w));
  return u;
}

#define GLD16(g, l) __builtin_amdgcn_global_load_lds( \
    (const __attribute__((address_space(1))) void*)(g), \
    (__attribute__((address_space(3))) void*)(l), 16, 0, 0)

// ---------------- kernel 1: pack weights (bf16) + bias (f32) ----------------
__global__ void cast_w_kernel(const float* __restrict__ wq, const float* __restrict__ wk,
                              const float* __restrict__ wv, const float* __restrict__ bq,
                              const float* __restrict__ bk, const float* __restrict__ bv,
                              unsigned short* __restrict__ wb, float* __restrict__ biasws) {
  int t = blockIdx.x * 256 + threadIdx.x;  // 0..196607, each handles 8 elems
  int base = t * 8;
  int n = base >> 12;       // output row 0..383 (q:0-127, k:128-255, v:256-383)
  int d = base & 4095;
  const float* src = (n < 128) ? (wq + (size_t)n * DM)
                   : (n < 256) ? (wk + (size_t)(n - 128) * DM)
                               : (wv + (size_t)(n - 256) * DM);
  float4 f0 = *(const float4*)(src + d);
  float4 f1 = *(const float4*)(src + d + 4);
  short8 v;
  v[0] = (short)f2bf(f0.x); v[1] = (short)f2bf(f0.y);
  v[2] = (short)f2bf(f0.z); v[3] = (short)f2bf(f0.w);
  v[4] = (short)f2bf(f1.x); v[5] = (short)f2bf(f1.y);
  v[6] = (short)f2bf(f1.z); v[7] = (short)f2bf(f1.w);
  *(short8*)(wb + base) = v;
  if (t < 384) biasws[t] = (t < 128) ? bq[t] : (t < 256) ? bk[t - 128] : bv[t - 256];
}

// ---------------- kernel 2: fused QKV GEMM + bias + RoPE ----------------
// BM=64, BN=128 (one head per block: 0=q 1=k 2=v), BK=64.
// 256 threads = 4 waves (2m x 2n), wave tile 32x64, acc 2x4.
// grid = 768 = 3 blocks/CU; XCD mapping co-runs one m-tile's 3 head-blocks.
// 2-phase double-buffered LDS; A-regs prefetched 2 K-steps ahead so the
// A-LDS write at iter t consumes loads issued at t-1 (HBM latency covered).
__global__ __launch_bounds__(256) void gemm_qkv_rope(
    const float* __restrict__ x, const unsigned short* __restrict__ wb,
    const float* __restrict__ biasws, const float* __restrict__ sing,
    const float* __restrict__ cosg, unsigned short* __restrict__ qb,
    unsigned short* __restrict__ kb, unsigned short* __restrict__ vb) {
  __shared__ __align__(16) short Alds[2 * 64 * 64];     // 16 KB, XOR-swizzled
  __shared__ __align__(16) short Blds[2 * 128 * 64];    // 32 KB, XOR-swizzled via src
  const int tid = threadIdx.x;
  const int l = tid & 63, w = tid >> 6;
  const int wm = w >> 1, wn = w & 1;
  const int l15 = l & 15, lg = l >> 4;

  // xcd-aware decomposition: 96 blocks per XCD = 32 m-tiles x 3 heads
  const int bid = blockIdx.x;
  const int xcd = bid & 7, j = bid >> 3;
  const int mloc = j / 3, head = j - mloc * 3;
  const int m0 = (xcd * 32 + mloc) * 64;

  f32x4 acc[2][4] = {};

  // A loads: lane pattern fully coalesced (16 lanes x 64B contiguous per row)
  const int ar0 = tid >> 4, ac4 = (tid & 15) * 4;       // rows ar0 + i*16
  const float* xsrc = x + (size_t)(m0 + ar0) * DM + ac4;
  // A LDS write: 8 bytes (4 bf16) at chunk (tid&15)>>1, half tid&1
  const int achunk = (tid & 15) >> 1, ahalf = tid & 1;
  // B staging: slot = i*256 + tid -> row i*32 + (tid>>3), chunk tid&7
  const int brow_ = tid >> 3, bchunk = tid & 7;
  const unsigned short* wbh = wb + (size_t)head * 128 * DM;

  // ---- prologue: stage tile 0 into buffer 0; prefetch A(tile1) to regs ----
  float4 aN0, aN1, aN2, aN3;   // A regs for tile t+1 (consumed at end of iter t)
  float4 aF0, aF1, aF2, aF3;   // A regs for tile t+2 (in flight)
  {
#pragma unroll
    for (int i = 0; i < 4; ++i) {
      float4 f = *(const float4*)(xsrc + (size_t)i * 16 * DM);
      int row = ar0 + i * 16;
      *(uint2*)&Alds[row * 64 + ((achunk ^ (row & 7)) * 8) + ahalf * 4] = cvt4(f);
    }
#pragma unroll
    for (int i = 0; i < 4; ++i) {
      int row = i * 32 + brow_;
      int slot = i * 256 + tid;
      const unsigned short* src = wbh + (size_t)row * DM + ((bchunk ^ (row & 7)) * 8);
      GLD16(src, (char*)Blds + slot * 16);
    }
    aN0 = *(const float4*)(xsrc + 64);
    aN1 = *(const float4*)(xsrc + (size_t)16 * DM + 64);
    aN2 = *(const float4*)(xsrc + (size_t)32 * DM + 64);
    aN3 = *(const float4*)(xsrc + (size_t)48 * DM + 64);
  }
  __syncthreads();

  int cur = 0;
#pragma unroll 1
  for (int t = 0; t < 63; ++t) {
    const int kB = (t + 1) * 64;
    // issue next B-tile global->LDS into buf^1
    char* bdst = (char*)Blds + (cur ^ 1) * 16384;
#pragma unroll
    for (int i = 0; i < 4; ++i) {
      int row = i * 32 + brow_;
      int slot = i * 256 + tid;
      const unsigned short* src = wbh + (size_t)row * DM + kB + ((bchunk ^ (row & 7)) * 8);
      GLD16(src, bdst + slot * 16);
    }
    // issue A-regs for tile t+2 (dummy k=0 on the last two iters)
    const int kF = (t < 62) ? (t + 2) * 64 : 0;
    aF0 = *(const float4*)(xsrc + kF);
    aF1 = *(const float4*)(xsrc + (size_t)16 * DM + kF);
    aF2 = *(const float4*)(xsrc + (size_t)32 * DM + kF);
    aF3 = *(const float4*)(xsrc + (size_t)48 * DM + kF);
    // compute current tile from buf[cur]
    const short* Ab = &Alds[cur * 4096];
    const short* Bb = &Blds[cur * 8192];
#pragma unroll
    for (int kc = 0; kc < 2; ++kc) {
      short8 af[2], bfr[4];
#pragma unroll
      for (int mi = 0; mi < 2; ++mi) {
        int r = wm * 32 + mi * 16 + l15;
        af[mi] = *(short8*)&Ab[r * 64 + ((kc * 32 + lg * 8) ^ ((r & 7) << 3))];
      }
#pragma unroll
      for (int ni = 0; ni < 4; ++ni) {
        int r = wn * 64 + ni * 16 + l15;
        bfr[ni] = *(short8*)&Bb[r * 64 + ((kc * 32 + lg * 8) ^ ((r & 7) << 3))];
      }
#pragma unroll
      for (int mi = 0; mi < 2; ++mi)
#pragma unroll
        for (int ni = 0; ni < 4; ++ni)
          acc[mi][ni] = __builtin_amdgcn_mfma_f32_16x16x32_bf16(af[mi], bfr[ni], acc[mi][ni], 0, 0, 0);
    }
    // stage A tile t+1 into LDS buf^1 from aN (loaded one iter ago)
    {
      short* Adst = &Alds[(cur ^ 1) * 4096];
      int r0 = ar0, r1 = ar0 + 16, r2 = ar0 + 32, r3 = ar0 + 48;
      *(uint2*)&Adst[r0 * 64 + ((achunk ^ (r0 & 7)) * 8) + ahalf * 4] = cvt4(aN0);
      *(uint2*)&Adst[r1 * 64 + ((achunk ^ (r1 & 7)) * 8) + ahalf * 4] = cvt4(aN1);
      *(uint2*)&Adst[r2 * 64 + ((achunk ^ (r2 & 7)) * 8) + ahalf * 4] = cvt4(aN2);
      *(uint2*)&Adst[r3 * 64 + ((achunk ^ (r3 & 7)) * 8) + ahalf * 4] = cvt4(aN3);
    }
    __syncthreads();   // drains vmcnt (B GLD16) + lgkm (A write); all waves synced
    aN0 = aF0; aN1 = aF1; aN2 = aF2; aN3 = aF3;   // SSA rotate (reg moves)
    cur ^= 1;
  }
  // epilogue compute: last tile (63), no staging
  {
    const short* Ab = &Alds[cur * 4096];
    const short* Bb = &Blds[cur * 8192];
#pragma unroll
    for (int kc = 0; kc < 2; ++kc) {
      short8 af[2], bfr[4];
#pragma unroll
      for (int mi = 0; mi < 2; ++mi) {
        int r = wm * 32 + mi * 16 + l15;
        af[mi] = *(short8*)&Ab[r * 64 + ((kc * 32 + lg * 8) ^ ((r & 7) << 3))];
      }
#pragma unroll
      for (int ni = 0; ni < 4; ++ni) {
        int r = wn * 64 + ni * 16 + l15;
        bfr[ni] = *(short8*)&Bb[r * 64 + ((kc * 32 + lg * 8) ^ ((r & 7) << 3))];
      }
#pragma unroll
      for (int mi = 0; mi < 2; ++mi)
#pragma unroll
        for (int ni = 0; ni < 4; ++ni)
          acc[mi][ni] = __builtin_amdgcn_mfma_f32_16x16x32_bf16(af[mi], bfr[ni], acc[mi][ni], 0, 0, 0);
    }
  }
  // epilogue: bias (+ RoPE for q,k — block-uniform), store bf16
  unsigned short* dst = (head == 0) ? qb : (head == 1) ? kb : vb;
#pragma unroll
  for (int mi = 0; mi < 2; ++mi)
#pragma unroll
    for (int ni = 0; ni < 4; ++ni) {
      int h = wn * 64 + ni * 16 + l15;   // 0..127 within head
      float bias = biasws[head * 128 + h];
      f32x4 a = acc[mi][ni];
#pragma unroll
      for (int j2 = 0; j2 < 4; ++j2) {
        int row = m0 + wm * 32 + mi * 16 + lg * 4 + j2;  // C/D: row=(lane>>4)*4+j
        float val = a[j2] + bias;
        if (head < 2) {
          // reference RoPE: out[h] = v[h]*cos[h] + v_sw[h]*sin[h],
          // v_sw[2i] = v_sw[2i+1] = v[2i+1] (odd element, repeated)
          int s = row & (SQ - 1);
          float cs = cosg[s * DH + h];
          float sn = sing[s * DH + h];
          float pr = __shfl_xor(val, 1, 64);      // partner col h^1 (same row)
          float sw = (l & 1) ? val : pr;          // odd h: self; even h: h+1
          val = val * cs + sw * sn;
        }
        dst[(size_t)row * DH + h] = f2bf(val);
      }
    }
}

// ---------------- kernel 2b: V -> V^T (per batch [128][4096]) ----------------
__global__ __launch_bounds__(256) void transpose_v(const unsigned short* __restrict__ vb,
                                                   unsigned short* __restrict__ vt) {
  __shared__ short T[128 * 72];
  const int b = blockIdx.x >> 6;
  const int s0 = (blockIdx.x & 63) * 64;
  const int t = threadIdx.x;
  {
    const int sl = t >> 2, dc = (t & 3) * 32;
    const unsigned short* src = vb + ((size_t)b * SQ + s0 + sl) * DH + dc;
#pragma unroll
    for (int i = 0; i < 4; ++i) {
      short8 v = *(const short8*)(src + i * 8);
#pragma unroll
      for (int j = 0; j < 8; ++j) T[(dc + i * 8 + j) * 72 + sl] = v[j];
    }
  }
  __syncthreads();
  {
    const int d = t >> 1, sh = (t & 1) * 32;
    unsigned short* dst = vt + ((size_t)b * DH + d) * SQ + s0 + sh;
#pragma unroll
    for (int i = 0; i < 4; ++i) {
      short8 w;
#pragma unroll
      for (int j = 0; j < 8; ++j) w[j] = T[d * 72 + sh + i * 8 + j];
      *(short8*)(dst + i * 8) = w;
    }
  }
}

// ---------------- kernel 3: causal flash attention ----------------
// 4 waves/block, one 16-row q-tile per block, KV steps strided across waves
// (flash-decoding split) with end merge. Swapped QK^T (S^T = K*Q): softmax is
// in-lane over 16 + 2 shuffles. Log2-domain scores. Defer-max (THR=8).
__global__ __launch_bounds__(256) void attn_kernel(
    const unsigned short* __restrict__ qb, const unsigned short* __restrict__ kb,
    const unsigned short* __restrict__ vt, float* __restrict__ out) {
  __shared__ __align__(16) float Obuf[3 * 16 * 132];  // 25344 B; aliased as P staging in loop
  __shared__ __align__(16) float Mlds[64];
  __shared__ __align__(16) float Llds[64];
  __shared__ __align__(16) float Clds[64];
  const int tid = threadIdx.x;
  const int w = tid >> 6, l = tid & 63;
  const int l15 = l & 15, lg = l >> 4;

  // schedule: slot = XCD (bi&7); 2 slots per batch; r-chunks balance CU totals
  const int bi = blockIdx.x;
  const int slot = bi & 7, p = slot & 1, batch = slot >> 1;
  const int idx = bi >> 3, ci = idx & 31, r = idx >> 5;
  const int a = ci + 32 * p;  // 0..63
  const int qt = (r == 0) ? a : (r == 1) ? 255 - a : (r == 2) ? 128 + a : 127 - a;
  const int q0 = qt * 16;
  const size_t bbase = (size_t)batch * SQ;
  const unsigned short* Kb = kb + bbase * DH;
  const unsigned short* Vt = vt + (size_t)batch * DH * SQ;
  short* Pw = (short*)Obuf + w * 1152;   // per-wave P staging [16][72] bf16

  // Q B-frags: col=l15 -> q row q0+l15; k-elems = kcd*32 + lg*8
  short8 qf[4];
  {
    const unsigned short* qp = qb + (bbase + q0 + l15) * DH + lg * 8;
#pragma unroll
    for (int kcd = 0; kcd < 4; ++kcd) qf[kcd] = *(const short8*)(qp + kcd * 32);
  }

  float m_r = -INFINITY, l_r = 0.f;
  f32x4 o[8] = {};
  const int nsteps = qt / 4 + 1;

  for (int st = w; st < nsteps; st += 4) {
    const int kv0 = st * 64;
    // --- K loads (A-frags: row=l15 -> kv, k=d) + QK^T ---
    short8 kf[4][4];
#pragma unroll
    for (int ni = 0; ni < 4; ++ni) {
      const unsigned short* kp = Kb + (size_t)(kv0 + ni * 16 + l15) * DH + lg * 8;
#pragma unroll
      for (int kcd = 0; kcd < 4; ++kcd) kf[ni][kcd] = *(const short8*)(kp + kcd * 32);
    }
    f32x4 sf[4] = {};
    __builtin_amdgcn_s_setprio(1);
#pragma unroll
    for (int kcd = 0; kcd < 4; ++kcd)
#pragma unroll
      for (int ni = 0; ni < 4; ++ni)
        sf[ni] = __builtin_amdgcn_mfma_f32_16x16x32_bf16(kf[ni][kcd], qf[kcd], sf[ni], 0, 0, 0);
    __builtin_amdgcn_s_setprio(0);

    // --- V^T loads issued early (consumed after softmax) ---
    short8 vf[8][2];
#pragma unroll
    for (int nd = 0; nd < 8; ++nd) {
      const unsigned short* vp = Vt + (size_t)(nd * 16 + l15) * SQ + kv0 + lg * 8;
      vf[nd][0] = *(const short8*)(vp);
      vf[nd][1] = *(const short8*)(vp + 32);
    }

    // --- scale (log2 domain) + causal mask (only diagonal step) ---
    float s[4][4];  // lane holds S^T[kv = kv0+ni*16+lg*4+j][q = q0+l15]
    if (st == nsteps - 1) {
#pragma unroll
      for (int ni = 0; ni < 4; ++ni)
#pragma unroll
        for (int j = 0; j < 4; ++j) {
          float v = sf[ni][j] * SCL2;
          if (kv0 + ni * 16 + lg * 4 + j > q0 + l15) v = -FLT_MAX;
          s[ni][j] = v;
        }
    } else {
#pragma unroll
      for (int ni = 0; ni < 4; ++ni)
#pragma unroll
        for (int j = 0; j < 4; ++j) s[ni][j] = sf[ni][j] * SCL2;
    }

    // --- softmax: in-lane max over 16, 2 shuffles across lg ---
    float tmx = s[0][0];
#pragma unroll
    for (int ni = 0; ni < 4; ++ni)
#pragma unroll
      for (int j = 0; j < 4; ++j) tmx = fmaxf(tmx, s[ni][j]);
    tmx = fmaxf(tmx, __shfl_xor(tmx, 16, 64));
    tmx = fmaxf(tmx, __shfl_xor(tmx, 32, 64));

    if (__any(tmx > m_r + 8.0f)) {          // defer-max: rescale only on real growth
      float mnew = fmaxf(m_r, tmx);
      float corr = exp2f(m_r - mnew);
      if (l < 16) Clds[w * 16 + l] = corr;  // redistribute corr q=l15 -> q=lg*4+j
      l_r *= corr; m_r = mnew;
      f32x4 c4 = *(f32x4*)&Clds[w * 16 + lg * 4];
#pragma unroll
      for (int nd = 0; nd < 8; ++nd)
#pragma unroll
        for (int j = 0; j < 4; ++j) o[nd][j] *= c4[j];
    }

    float rs = 0.f;
    float pp[4][4];
#pragma unroll
    for (int ni = 0; ni < 4; ++ni)
#pragma unroll
      for (int j = 0; j < 4; ++j) {
        pp[ni][j] = exp2f(s[ni][j] - m_r);
        rs += pp[ni][j];
      }
    rs += __shfl_xor(rs, 16, 64);
    rs += __shfl_xor(rs, 32, 64);
    l_r += rs;

    // --- P -> bf16 via cvt_pk, through per-wave LDS to A-frag layout ---
#pragma unroll
    for (int ni = 0; ni < 4; ++ni) {
      uint32 lo, hi;
      asm volatile("v_cvt_pk_bf16_f32 %0, %1, %2" : "=v"(lo) : "v"(pp[ni][0]), "v"(pp[ni][1]));
      asm volatile("v_cvt_pk_bf16_f32 %0, %1, %2" : "=v"(hi) : "v"(pp[ni][2]), "v"(pp[ni][3]));
      uint2 u; u.x = lo; u.y = hi;
      *(uint2*)&Pw[l15 * 72 + ni * 16 + lg * 4] = u;
    }
    short8 pa0 = *(short8*)&Pw[l15 * 72 + lg * 8];
    short8 pa1 = *(short8*)&Pw[l15 * 72 + 32 + lg * 8];
    __builtin_amdgcn_s_setprio(1);
#pragma unroll
    for (int nd = 0; nd < 8; ++nd) {
      o[nd] = __builtin_amdgcn_mfma_f32_16x16x32_bf16(pa0, vf[nd][0], o[nd], 0, 0, 0);
      o[nd] = __builtin_amdgcn_mfma_f32_16x16x32_bf16(pa1, vf[nd][1], o[nd], 0, 0, 0);
    }
    __builtin_amdgcn_s_setprio(0);
  }

  // --- merge the 4 waves' online states ---
  if (l < 16) { Mlds[w * 16 + l] = m_r; Llds[w * 16 + l] = l_r; }
  __syncthreads();   // P-staging region done; M/L visible
  if (w > 0) {
#pragma unroll
    for (int nd = 0; nd < 8; ++nd)
#pragma unroll
      for (int j = 0; j < 4; ++j)
        Obuf[(w - 1) * 2112 + (lg * 4 + j) * 132 + nd * 16 + l15] = o[nd][j];
  }
  __syncthreads();
  if (w == 0) {
    float al[4][4], Lt[4];
#pragma unroll
    for (int j = 0; j < 4; ++j) {
      int q = lg * 4 + j;
      float M = Mlds[q];
#pragma unroll
      for (int ww = 1; ww < 4; ++ww) M = fmaxf(M, Mlds[ww * 16 + q]);
      float sL = 0.f;
#pragma unroll
      for (int ww = 0; ww < 4; ++ww) {
        float aa = exp2f(Mlds[ww * 16 + q] - M);
        al[ww][j] = aa; sL += aa * Llds[ww * 16 + q];
      }
      Lt[j] = sL;
    }
#pragma unroll
    for (int nd = 0; nd < 8; ++nd)
#pragma unroll
      for (int j = 0; j < 4; ++j) {
        float acc2 = al[0][j] * o[nd][j];
#pragma unroll
        for (int ww = 1; ww < 4; ++ww)
          acc2 += al[ww][j] * Obuf[(ww - 1) * 2112 + (lg * 4 + j) * 132 + nd * 16 + l15];
        out[(bbase + q0 + lg * 4 + j) * DH + nd * 16 + l15] = acc2 / Lt[j];
      }
  }
}

extern "C" void kernel_launch(void* const* d_in, const int* in_sizes, int n_in,
                              void* d_out, int out_size, void* d_ws, size_t ws_size,
                              hipStream_t stream) {
  const float* x    = (const float*)d_in[0];
  const float* wq   = (const float*)d_in[1];
  const float* bq   = (const float*)d_in[2];
  const float* wk   = (const float*)d_in[3];
  const float* bk   = (const float*)d_in[4];
  const float* wv   = (const float*)d_in[5];
  const float* bv   = (const float*)d_in[6];
  const float* sing = (const float*)d_in[7];
  const float* cosg = (const float*)d_in[8];
  float* out = (float*)d_out;

  char* ws = (char*)d_ws;
  unsigned short* wb = (unsigned short*)ws;                        // 3,145,728 B
  float* biasws = (float*)(ws + 3145728);                          // 1,536 B
  unsigned short* qb = (unsigned short*)(ws + 3147264);            // 4 MB
  unsigned short* kb = (unsigned short*)(ws + 3147264 + 4194304);  // 4 MB
  unsigned short* vb = (unsigned short*)(ws + 3147264 + 2 * 4194304);  // 4 MB
  unsigned short* vt = (unsigned short*)(ws + 3147264 + 3 * 4194304);  // 4 MB (V^T)
  // total ws use: ~19.9 MB

  cast_w_kernel<<<768, 256, 0, stream>>>(wq, wk, wv, bq, bk, bv, wb, biasws);
  gemm_qkv_rope<<<768, 256, 0, stream>>>(x, wb, biasws, sing, cosg, qb, kb, vb);
  transpose_v<<<256, 256, 0, stream>>>(vb, vt);
  attn_kernel<<<1024, 256, 0, stream>>>(qb, kb, vt, out);
}

// Round 8
// 237.932 us; speedup vs baseline: 1.7553x; 1.0116x over previous
//
#include <hip/hip_runtime.h>
#include <hip/hip_bf16.h>
#include <float.h>
#include <math.h>

typedef float f32x4 __attribute__((ext_vector_type(4)));
typedef short short8 __attribute__((ext_vector_type(8)));
typedef unsigned int uint32;

#define NB 4
#define SQ 4096
#define DM 4096
#define DH 128
#define LOG2E 1.44269504088896f
#define SCALE 0.0883883476483184f   // 1/sqrt(128)
#define SCL2 (SCALE * LOG2E)        // fold into log2 domain

__device__ __forceinline__ unsigned short f2bf(float f) {
  union { float f; unsigned u; } x; x.f = f;
  unsigned r = x.u + 0x7FFFu + ((x.u >> 16) & 1u);
  return (unsigned short)(r >> 16);
}

__device__ __forceinline__ uint2 cvt4(float4 f) {
  uint2 u;
  asm("v_cvt_pk_bf16_f32 %0, %1, %2" : "=v"(u.x) : "v"(f.x), "v"(f.y));
  asm("v_cvt_pk_bf16_f32 %0, %1, %2" : "=v"(u.y) : "v"(f.z), "v"(f.w));
  return u;
}

#define GLD16(g, l) __builtin_amdgcn_global_load_lds( \
    (const __attribute__((address_space(1))) void*)(g), \
    (__attribute__((address_space(3))) void*)(l), 16, 0, 0)

// ---------------- kernel 1: pack weights (bf16) + bias (f32) ----------------
__global__ void cast_w_kernel(const float* __restrict__ wq, const float* __restrict__ wk,
                              const float* __restrict__ wv, const float* __restrict__ bq,
                              const float* __restrict__ bk, const float* __restrict__ bv,
                              unsigned short* __restrict__ wb, float* __restrict__ biasws) {
  int t = blockIdx.x * 256 + threadIdx.x;  // 0..196607, each handles 8 elems
  int base = t * 8;
  int n = base >> 12;       // output row 0..383 (q:0-127, k:128-255, v:256-383)
  int d = base & 4095;
  const float* src = (n < 128) ? (wq + (size_t)n * DM)
                   : (n < 256) ? (wk + (size_t)(n - 128) * DM)
                               : (wv + (size_t)(n - 256) * DM);
  float4 f0 = *(const float4*)(src + d);
  float4 f1 = *(const float4*)(src + d + 4);
  short8 v;
  v[0] = (short)f2bf(f0.x); v[1] = (short)f2bf(f0.y);
  v[2] = (short)f2bf(f0.z); v[3] = (short)f2bf(f0.w);
  v[4] = (short)f2bf(f1.x); v[5] = (short)f2bf(f1.y);
  v[6] = (short)f2bf(f1.z); v[7] = (short)f2bf(f1.w);
  *(short8*)(wb + base) = v;
  if (t < 384) biasws[t] = (t < 128) ? bq[t] : (t < 256) ? bk[t - 128] : bv[t - 256];
}

// ---------------- kernel 2: fused QKV GEMM + bias + RoPE ----------------
// BM=64, BN=128 (one head per block), BK=64. 4 waves (2m x 2n), 3 blocks/CU.
// T4 counted-vmcnt pipeline: one raw s_barrier/iter, NO vmcnt(0) drain in the
// loop. Fixed 8-VMEM/iter issue order (4 GLD16 B(t+1), then 4 A f32 loads for
// t+2). Top-of-iter wait = vmcnt(4): only B(t) DMA (aged one full iteration);
// the A loads keep flying. A-regs ping-pong via 2-unrolled call sites (no reg
// copies of in-flight loads -> no forced early waits).
// Hazard notes: GLD16/A-writes target buf^1; readers of buf^1 finished before
// the PREVIOUS top barrier (all waves crossed it), so one barrier/iter is
// sufficient. sched_barrier(0) pins GLD16 below s_barrier (DMA vs LDS-read
// race otherwise). Epilogue drains vmcnt(0) (dummy-load DCE-safe).
__global__ __launch_bounds__(256) void gemm_qkv_rope(
    const float* __restrict__ x, const unsigned short* __restrict__ wb,
    const float* __restrict__ biasws, const float* __restrict__ sing,
    const float* __restrict__ cosg, unsigned short* __restrict__ qb,
    unsigned short* __restrict__ kb, unsigned short* __restrict__ vb) {
  __shared__ __align__(16) short Alds[2 * 64 * 64];     // 16 KB, XOR-swizzled
  __shared__ __align__(16) short Blds[2 * 128 * 64];    // 32 KB, XOR-swizzled via src
  const int tid = threadIdx.x;
  const int l = tid & 63, w = tid >> 6;
  const int wm = w >> 1, wn = w & 1;
  const int l15 = l & 15, lg = l >> 4;

  // xcd-aware decomposition: 96 blocks per XCD = 32 m-tiles x 3 heads
  const int bid = blockIdx.x;
  const int xcd = bid & 7, j = bid >> 3;
  const int mloc = j / 3, head = j - mloc * 3;
  const int m0 = (xcd * 32 + mloc) * 64;

  f32x4 acc[2][4] = {};

  // A loads: 16 lanes x 128B contiguous per row (4 rows per thread-quad set)
  const int ar0 = tid >> 4, ac4 = (tid & 15) * 4;       // rows ar0 + i*16
  const float* xsrc = x + (size_t)(m0 + ar0) * DM + ac4;
  // A LDS write: 8 bytes (4 bf16) at chunk (tid&15)>>1, half tid&1
  const int achunk = (tid & 15) >> 1, ahalf = tid & 1;
  // B staging: slot = i*256 + tid -> row i*32 + (tid>>3), chunk tid&7
  const int brow_ = tid >> 3, bchunk = tid & 7;
  const unsigned short* wbh = wb + (size_t)head * 128 * DM;

  float4 a00, a01, a02, a03;   // A reg group 0
  float4 a10, a11, a12, a13;   // A reg group 1

  // ---- prologue: A(0)->Alds[0] direct; GLD16 B(0); A(1)->group0 ----
  {
#pragma unroll
    for (int i = 0; i < 4; ++i) {
      float4 f = *(const float4*)(xsrc + (size_t)i * 16 * DM);
      int row = ar0 + i * 16;
      *(uint2*)&Alds[row * 64 + ((achunk ^ (row & 7)) * 8) + ahalf * 4] = cvt4(f);
    }
#pragma unroll
    for (int i = 0; i < 4; ++i) {
      int row = i * 32 + brow_;
      int slot = i * 256 + tid;
      GLD16(wbh + (size_t)row * DM + ((bchunk ^ (row & 7)) * 8), (char*)Blds + slot * 16);
    }
    a00 = *(const float4*)(xsrc + 64);
    a01 = *(const float4*)(xsrc + (size_t)16 * DM + 64);
    a02 = *(const float4*)(xsrc + (size_t)32 * DM + 64);
    a03 = *(const float4*)(xsrc + (size_t)48 * DM + 64);
  }

  // one pipelined K-step: tile t computed, B(t+1) staged, A(t+1) written,
  // A(t+2) loads issued into aF. CUR is a compile-time 0/1 after inlining.
  auto giter = [&](int t, int CUR,
                   float4& n0, float4& n1, float4& n2, float4& n3,
                   float4& f0, float4& f1, float4& f2, float4& f3) {
    asm volatile("s_waitcnt vmcnt(4) lgkmcnt(0)" ::: "memory");
    __builtin_amdgcn_sched_barrier(0);
    __builtin_amdgcn_s_barrier();
    __builtin_amdgcn_sched_barrier(0);
    // stage B(t+1) -> buf^1 (4 GLD16, oldest VMEM group of this iter)
    const int kB = (t + 1) * 64;
    char* bdst = (char*)Blds + (CUR ^ 1) * 16384;
#pragma unroll
    for (int i = 0; i < 4; ++i) {
      int row = i * 32 + brow_;
      int slot = i * 256 + tid;
      GLD16(wbh + (size_t)row * DM + kB + ((bchunk ^ (row & 7)) * 8), bdst + slot * 16);
    }
    __builtin_amdgcn_sched_barrier(0);   // pin GLD16 before A loads (vmcnt order)
    // issue A(t+2) -> aF (4 VMEM, newest group)
    const int kF = (t < 62) ? (t + 2) * 64 : 0;
    f0 = *(const float4*)(xsrc + kF);
    f1 = *(const float4*)(xsrc + (size_t)16 * DM + kF);
    f2 = *(const float4*)(xsrc + (size_t)32 * DM + kF);
    f3 = *(const float4*)(xsrc + (size_t)48 * DM + kF);
    // compute tile t from buf[CUR]
    const short* Ab = &Alds[CUR * 4096];
    const short* Bb = &Blds[CUR * 8192];
#pragma unroll
    for (int kc = 0; kc < 2; ++kc) {
      short8 af[2], bfr[4];
#pragma unroll
      for (int mi = 0; mi < 2; ++mi) {
        int r = wm * 32 + mi * 16 + l15;
        af[mi] = *(short8*)&Ab[r * 64 + ((kc * 32 + lg * 8) ^ ((r & 7) << 3))];
      }
#pragma unroll
      for (int ni = 0; ni < 4; ++ni) {
        int r = wn * 64 + ni * 16 + l15;
        bfr[ni] = *(short8*)&Bb[r * 64 + ((kc * 32 + lg * 8) ^ ((r & 7) << 3))];
      }
#pragma unroll
      for (int mi = 0; mi < 2; ++mi)
#pragma unroll
        for (int ni = 0; ni < 4; ++ni)
          acc[mi][ni] = __builtin_amdgcn_mfma_f32_16x16x32_bf16(af[mi], bfr[ni], acc[mi][ni], 0, 0, 0);
    }
    // stage A(t+1) from aN (compiler inserts exact counted vmcnt(8) here)
    {
      short* Adst = &Alds[(CUR ^ 1) * 4096];
      int r0 = ar0, r1 = ar0 + 16, r2 = ar0 + 32, r3 = ar0 + 48;
      *(uint2*)&Adst[r0 * 64 + ((achunk ^ (r0 & 7)) * 8) + ahalf * 4] = cvt4(n0);
      *(uint2*)&Adst[r1 * 64 + ((achunk ^ (r1 & 7)) * 8) + ahalf * 4] = cvt4(n1);
      *(uint2*)&Adst[r2 * 64 + ((achunk ^ (r2 & 7)) * 8) + ahalf * 4] = cvt4(n2);
      *(uint2*)&Adst[r3 * 64 + ((achunk ^ (r3 & 7)) * 8) + ahalf * 4] = cvt4(n3);
    }
  };

#pragma unroll 1
  for (int t = 0; t < 62; t += 2) {
    giter(t,     0, a00, a01, a02, a03, a10, a11, a12, a13);
    giter(t + 1, 1, a10, a11, a12, a13, a00, a01, a02, a03);
  }
  giter(62, 0, a00, a01, a02, a03, a10, a11, a12, a13);

  // epilogue: tile 63 from buf[1] (full drain once; dummy-load DCE-safe)
  {
    asm volatile("s_waitcnt vmcnt(0) lgkmcnt(0)" ::: "memory");
    __builtin_amdgcn_sched_barrier(0);
    __builtin_amdgcn_s_barrier();
    __builtin_amdgcn_sched_barrier(0);
    const short* Ab = &Alds[4096];
    const short* Bb = &Blds[8192];
#pragma unroll
    for (int kc = 0; kc < 2; ++kc) {
      short8 af[2], bfr[4];
#pragma unroll
      for (int mi = 0; mi < 2; ++mi) {
        int r = wm * 32 + mi * 16 + l15;
        af[mi] = *(short8*)&Ab[r * 64 + ((kc * 32 + lg * 8) ^ ((r & 7) << 3))];
      }
#pragma unroll
      for (int ni = 0; ni < 4; ++ni) {
        int r = wn * 64 + ni * 16 + l15;
        bfr[ni] = *(short8*)&Bb[r * 64 + ((kc * 32 + lg * 8) ^ ((r & 7) << 3))];
      }
#pragma unroll
      for (int mi = 0; mi < 2; ++mi)
#pragma unroll
        for (int ni = 0; ni < 4; ++ni)
          acc[mi][ni] = __builtin_amdgcn_mfma_f32_16x16x32_bf16(af[mi], bfr[ni], acc[mi][ni], 0, 0, 0);
    }
  }

  // epilogue: bias (+ RoPE for q,k — block-uniform), store bf16
  unsigned short* dst = (head == 0) ? qb : (head == 1) ? kb : vb;
#pragma unroll
  for (int mi = 0; mi < 2; ++mi)
#pragma unroll
    for (int ni = 0; ni < 4; ++ni) {
      int h = wn * 64 + ni * 16 + l15;   // 0..127 within head
      float bias = biasws[head * 128 + h];
      f32x4 a = acc[mi][ni];
#pragma unroll
      for (int j2 = 0; j2 < 4; ++j2) {
        int row = m0 + wm * 32 + mi * 16 + lg * 4 + j2;  // C/D: row=(lane>>4)*4+j
        float val = a[j2] + bias;
        if (head < 2) {
          // reference RoPE: out[h] = v[h]*cos[h] + v_sw[h]*sin[h],
          // v_sw[2i] = v_sw[2i+1] = v[2i+1] (odd element, repeated)
          int s = row & (SQ - 1);
          float cs = cosg[s * DH + h];
          float sn = sing[s * DH + h];
          float pr = __shfl_xor(val, 1, 64);      // partner col h^1 (same row)
          float sw = (l & 1) ? val : pr;          // odd h: self; even h: h+1
          val = val * cs + sw * sn;
        }
        dst[(size_t)row * DH + h] = f2bf(val);
      }
    }
}

// ---------------- kernel 2b: V -> V^T (per batch [128][4096]) ----------------
__global__ __launch_bounds__(256) void transpose_v(const unsigned short* __restrict__ vb,
                                                   unsigned short* __restrict__ vt) {
  __shared__ short T[128 * 72];
  const int b = blockIdx.x >> 6;
  const int s0 = (blockIdx.x & 63) * 64;
  const int t = threadIdx.x;
  {
    const int sl = t >> 2, dc = (t & 3) * 32;
    const unsigned short* src = vb + ((size_t)b * SQ + s0 + sl) * DH + dc;
#pragma unroll
    for (int i = 0; i < 4; ++i) {
      short8 v = *(const short8*)(src + i * 8);
#pragma unroll
      for (int j = 0; j < 8; ++j) T[(dc + i * 8 + j) * 72 + sl] = v[j];
    }
  }
  __syncthreads();
  {
    const int d = t >> 1, sh = (t & 1) * 32;
    unsigned short* dst = vt + ((size_t)b * DH + d) * SQ + s0 + sh;
#pragma unroll
    for (int i = 0; i < 4; ++i) {
      short8 w;
#pragma unroll
      for (int j = 0; j < 8; ++j) w[j] = T[d * 72 + sh + i * 8 + j];
      *(short8*)(dst + i * 8) = w;
    }
  }
}

// ---------------- kernel 3: causal flash attention ----------------
// 4 waves/block, one 16-row q-tile per block, KV steps strided across waves
// (flash-decoding split) with end merge. Swapped QK^T (S^T = K*Q): softmax is
// in-lane over 16 + 2 shuffles. Log2-domain scores. Defer-max (THR=8).
__global__ __launch_bounds__(256) void attn_kernel(
    const unsigned short* __restrict__ qb, const unsigned short* __restrict__ kb,
    const unsigned short* __restrict__ vt, float* __restrict__ out) {
  __shared__ __align__(16) float Obuf[3 * 16 * 132];  // 25344 B; aliased as P staging in loop
  __shared__ __align__(16) float Mlds[64];
  __shared__ __align__(16) float Llds[64];
  __shared__ __align__(16) float Clds[64];
  const int tid = threadIdx.x;
  const int w = tid >> 6, l = tid & 63;
  const int l15 = l & 15, lg = l >> 4;

  // schedule: slot = XCD (bi&7); 2 slots per batch; r-chunks balance CU totals
  const int bi = blockIdx.x;
  const int slot = bi & 7, p = slot & 1, batch = slot >> 1;
  const int idx = bi >> 3, ci = idx & 31, r = idx >> 5;
  const int a = ci + 32 * p;  // 0..63
  const int qt = (r == 0) ? a : (r == 1) ? 255 - a : (r == 2) ? 128 + a : 127 - a;
  const int q0 = qt * 16;
  const size_t bbase = (size_t)batch * SQ;
  const unsigned short* Kb = kb + bbase * DH;
  const unsigned short* Vt = vt + (size_t)batch * DH * SQ;
  short* Pw = (short*)Obuf + w * 1152;   // per-wave P staging [16][72] bf16

  // Q B-frags: col=l15 -> q row q0+l15; k-elems = kcd*32 + lg*8
  short8 qf[4];
  {
    const unsigned short* qp = qb + (bbase + q0 + l15) * DH + lg * 8;
#pragma unroll
    for (int kcd = 0; kcd < 4; ++kcd) qf[kcd] = *(const short8*)(qp + kcd * 32);
  }

  float m_r = -INFINITY, l_r = 0.f;
  f32x4 o[8] = {};
  const int nsteps = qt / 4 + 1;

  for (int st = w; st < nsteps; st += 4) {
    const int kv0 = st * 64;
    // --- K loads (A-frags: row=l15 -> kv, k=d) + QK^T ---
    short8 kf[4][4];
#pragma unroll
    for (int ni = 0; ni < 4; ++ni) {
      const unsigned short* kp = Kb + (size_t)(kv0 + ni * 16 + l15) * DH + lg * 8;
#pragma unroll
      for (int kcd = 0; kcd < 4; ++kcd) kf[ni][kcd] = *(const short8*)(kp + kcd * 32);
    }
    f32x4 sf[4] = {};
    __builtin_amdgcn_s_setprio(1);
#pragma unroll
    for (int kcd = 0; kcd < 4; ++kcd)
#pragma unroll
      for (int ni = 0; ni < 4; ++ni)
        sf[ni] = __builtin_amdgcn_mfma_f32_16x16x32_bf16(kf[ni][kcd], qf[kcd], sf[ni], 0, 0, 0);
    __builtin_amdgcn_s_setprio(0);

    // --- V^T loads issued early (consumed after softmax) ---
    short8 vf[8][2];
#pragma unroll
    for (int nd = 0; nd < 8; ++nd) {
      const unsigned short* vp = Vt + (size_t)(nd * 16 + l15) * SQ + kv0 + lg * 8;
      vf[nd][0] = *(const short8*)(vp);
      vf[nd][1] = *(const short8*)(vp + 32);
    }

    // --- scale (log2 domain) + causal mask (only diagonal step) ---
    float s[4][4];  // lane holds S^T[kv = kv0+ni*16+lg*4+j][q = q0+l15]
    if (st == nsteps - 1) {
#pragma unroll
      for (int ni = 0; ni < 4; ++ni)
#pragma unroll
        for (int j = 0; j < 4; ++j) {
          float v = sf[ni][j] * SCL2;
          if (kv0 + ni * 16 + lg * 4 + j > q0 + l15) v = -FLT_MAX;
          s[ni][j] = v;
        }
    } else {
#pragma unroll
      for (int ni = 0; ni < 4; ++ni)
#pragma unroll
        for (int j = 0; j < 4; ++j) s[ni][j] = sf[ni][j] * SCL2;
    }

    // --- softmax: in-lane max over 16, 2 shuffles across lg ---
    float tmx = s[0][0];
#pragma unroll
    for (int ni = 0; ni < 4; ++ni)
#pragma unroll
      for (int j = 0; j < 4; ++j) tmx = fmaxf(tmx, s[ni][j]);
    tmx = fmaxf(tmx, __shfl_xor(tmx, 16, 64));
    tmx = fmaxf(tmx, __shfl_xor(tmx, 32, 64));

    if (__any(tmx > m_r + 8.0f)) {          // defer-max: rescale only on real growth
      float mnew = fmaxf(m_r, tmx);
      float corr = exp2f(m_r - mnew);
      if (l < 16) Clds[w * 16 + l] = corr;  // redistribute corr q=l15 -> q=lg*4+j
      l_r *= corr; m_r = mnew;
      f32x4 c4 = *(f32x4*)&Clds[w * 16 + lg * 4];
#pragma unroll
      for (int nd = 0; nd < 8; ++nd)
#pragma unroll
        for (int j = 0; j < 4; ++j) o[nd][j] *= c4[j];
    }

    float rs = 0.f;
    float pp[4][4];
#pragma unroll
    for (int ni = 0; ni < 4; ++ni)
#pragma unroll
      for (int j = 0; j < 4; ++j) {
        pp[ni][j] = exp2f(s[ni][j] - m_r);
        rs += pp[ni][j];
      }
    rs += __shfl_xor(rs, 16, 64);
    rs += __shfl_xor(rs, 32, 64);
    l_r += rs;

    // --- P -> bf16 via cvt_pk, through per-wave LDS to A-frag layout ---
#pragma unroll
    for (int ni = 0; ni < 4; ++ni) {
      uint32 lo, hi;
      asm volatile("v_cvt_pk_bf16_f32 %0, %1, %2" : "=v"(lo) : "v"(pp[ni][0]), "v"(pp[ni][1]));
      asm volatile("v_cvt_pk_bf16_f32 %0, %1, %2" : "=v"(hi) : "v"(pp[ni][2]), "v"(pp[ni][3]));
      uint2 u; u.x = lo; u.y = hi;
      *(uint2*)&Pw[l15 * 72 + ni * 16 + lg * 4] = u;
    }
    short8 pa0 = *(short8*)&Pw[l15 * 72 + lg * 8];
    short8 pa1 = *(short8*)&Pw[l15 * 72 + 32 + lg * 8];
    __builtin_amdgcn_s_setprio(1);
#pragma unroll
    for (int nd = 0; nd < 8; ++nd) {
      o[nd] = __builtin_amdgcn_mfma_f32_16x16x32_bf16(pa0, vf[nd][0], o[nd], 0, 0, 0);
      o[nd] = __builtin_amdgcn_mfma_f32_16x16x32_bf16(pa1, vf[nd][1], o[nd], 0, 0, 0);
    }
    __builtin_amdgcn_s_setprio(0);
  }

  // --- merge the 4 waves' online states ---
  if (l < 16) { Mlds[w * 16 + l] = m_r; Llds[w * 16 + l] = l_r; }
  __syncthreads();   // P-staging region done; M/L visible
  if (w > 0) {
#pragma unroll
    for (int nd = 0; nd < 8; ++nd)
#pragma unroll
      for (int j = 0; j < 4; ++j)
        Obuf[(w - 1) * 2112 + (lg * 4 + j) * 132 + nd * 16 + l15] = o[nd][j];
  }
  __syncthreads();
  if (w == 0) {
    float al[4][4], Lt[4];
#pragma unroll
    for (int j = 0; j < 4; ++j) {
      int q = lg * 4 + j;
      float M = Mlds[q];
#pragma unroll
      for (int ww = 1; ww < 4; ++ww) M = fmaxf(M, Mlds[ww * 16 + q]);
      float sL = 0.f;
#pragma unroll
      for (int ww = 0; ww < 4; ++ww) {
        float aa = exp2f(Mlds[ww * 16 + q] - M);
        al[ww][j] = aa; sL += aa * Llds[ww * 16 + q];
      }
      Lt[j] = sL;
    }
#pragma unroll
    for (int nd = 0; nd < 8; ++nd)
#pragma unroll
      for (int j = 0; j < 4; ++j) {
        float acc2 = al[0][j] * o[nd][j];
#pragma unroll
        for (int ww = 1; ww < 4; ++ww)
          acc2 += al[ww][j] * Obuf[(ww - 1) * 2112 + (lg * 4 + j) * 132 + nd * 16 + l15];
        out[(bbase + q0 + lg * 4 + j) * DH + nd * 16 + l15] = acc2 / Lt[j];
      }
  }
}

extern "C" void kernel_launch(void* const* d_in, const int* in_sizes, int n_in,
                              void* d_out, int out_size, void* d_ws, size_t ws_size,
                              hipStream_t stream) {
  const float* x    = (const float*)d_in[0];
  const float* wq   = (const float*)d_in[1];
  const float* bq   = (const float*)d_in[2];
  const float* wk   = (const float*)d_in[3];
  const float* bk   = (const float*)d_in[4];
  const float* wv   = (const float*)d_in[5];
  const float* bv   = (const float*)d_in[6];
  const float* sing = (const float*)d_in[7];
  const float* cosg = (const float*)d_in[8];
  float* out = (float*)d_out;

  char* ws = (char*)d_ws;
  unsigned short* wb = (unsigned short*)ws;                        // 3,145,728 B
  float* biasws = (float*)(ws + 3145728);                          // 1,536 B
  unsigned short* qb = (unsigned short*)(ws + 3147264);            // 4 MB
  unsigned short* kb = (unsigned short*)(ws + 3147264 + 4194304);  // 4 MB
  unsigned short* vb = (unsigned short*)(ws + 3147264 + 2 * 4194304);  // 4 MB
  unsigned short* vt = (unsigned short*)(ws + 3147264 + 3 * 4194304);  // 4 MB (V^T)
  // total ws use: ~19.9 MB

  cast_w_kernel<<<768, 256, 0, stream>>>(wq, wk, wv, bq, bk, bv, wb, biasws);
  gemm_qkv_rope<<<768, 256, 0, stream>>>(x, wb, biasws, sing, cosg, qb, kb, vb);
  transpose_v<<<256, 256, 0, stream>>>(vb, vt);
  attn_kernel<<<1024, 256, 0, stream>>>(qb, kb, vt, out);
}